// Round 12
// baseline (305.182 us; speedup 1.0000x reference)
//
#include <hip/hip_runtime.h>

#define T_SEQ 2048
#define DM 1024
#define NH 16
#define DKH 64
#define NB 2
#define M_ROWS (NB * T_SEQ)  // 4096
#define QSCALE 0.18033688011112042f  // 0.125 * log2(e): exp2 domain

using bf16x8 = __attribute__((ext_vector_type(8))) __bf16;
using f32x4  = __attribute__((ext_vector_type(4))) float;
using halfx4 = __attribute__((ext_vector_type(4))) __fp16;
using halfx2 = __attribute__((ext_vector_type(2))) __fp16;

__device__ __forceinline__ short f2bf(float f) {
  unsigned u = __builtin_bit_cast(unsigned, f);
  u += 0x7fffu + ((u >> 16) & 1u);
  return (short)(u >> 16);
}

#if defined(__has_builtin) && __has_builtin(__builtin_amdgcn_cvt_pk_bf16_f32)
using bf16x2 = __attribute__((ext_vector_type(2))) __bf16;
__device__ __forceinline__ short2 pk2(float a, float b) {
  bf16x2 r = __builtin_amdgcn_cvt_pk_bf16_f32(a, b);
  return __builtin_bit_cast(short2, r);
}
#else
__device__ __forceinline__ short2 pk2(float a, float b) {
  short2 r; r.x = f2bf(a); r.y = f2bf(b); return r;
}
#endif

__device__ __forceinline__ short2 pkh(float a, float b) {  // f32x2 -> f16x2 (RTZ)
  halfx2 r = __builtin_amdgcn_cvt_pkrtz(a, b);
  return __builtin_bit_cast(short2, r);
}

#if defined(__has_builtin) && __has_builtin(__builtin_amdgcn_exp2f)
__device__ __forceinline__ float fexp2(float x) { return __builtin_amdgcn_exp2f(x); }
#else
__device__ __forceinline__ float fexp2(float x) { return exp2f(x); }
#endif

#define MFMA16F16 __builtin_amdgcn_mfma_f32_16x16x16f16

#define GLD16(g, l)                                                            \
  __builtin_amdgcn_global_load_lds(                                            \
      (const __attribute__((address_space(1))) void*)(g),                      \
      (__attribute__((address_space(3))) void*)(l), 16, 0, 0)

// ---------- prep: fp32 -> bf16 of q,k,v; mask -> additive float ----------
__global__ __launch_bounds__(256) void prep_x(
    const float* __restrict__ q, const float* __restrict__ k,
    const float* __restrict__ v, const int* __restrict__ mask,
    short* __restrict__ dst, float* __restrict__ mf) {
  const float* s = blockIdx.z == 0 ? q : (blockIdx.z == 1 ? k : v);
  short* d = dst + (size_t)blockIdx.z * (M_ROWS * DM);
  const int n4 = M_ROWS * DM / 4;
  for (int i = blockIdx.x * 256 + threadIdx.x; i < n4; i += gridDim.x * 256) {
    float4 f = *(const float4*)(s + i * 4);
    short2 a = pk2(f.x, f.y), b = pk2(f.z, f.w);
    short4 o = {a.x, a.y, b.x, b.y};
    *(short4*)(d + i * 4) = o;
  }
  if (blockIdx.z == 0 && blockIdx.x < 4) {
    int i = (blockIdx.x * 256 + threadIdx.x) * 4;
    int4 m = *(const int4*)(mask + i);
    float4 o = {m.x ? 0.f : -1e38f, m.y ? 0.f : -1e38f,
                m.z ? 0.f : -1e38f, m.w ? 0.f : -1e38f};
    *(float4*)(mf + i) = o;
  }
}

// ---------- prep: W [k][n] fp32 -> Wt [n][k] bf16 (4 matrices) ----------
__global__ __launch_bounds__(256) void prep_w(
    const float* __restrict__ w0, const float* __restrict__ w1,
    const float* __restrict__ w2, const float* __restrict__ w3,
    short* __restrict__ dst) {
  __shared__ short T[64][72];
  const float* W = blockIdx.z == 0 ? w0 : blockIdx.z == 1 ? w1
                   : blockIdx.z == 2 ? w2 : w3;
  short* D = dst + (size_t)blockIdx.z * (DM * DM);
  const int k0 = blockIdx.x * 64, n0 = blockIdx.y * 64;
  const int r = threadIdx.x >> 2, cs = (threadIdx.x & 3) * 16;
#pragma unroll
  for (int j = 0; j < 4; ++j) {
    float4 f = *(const float4*)(W + (size_t)(k0 + r) * DM + n0 + cs + j * 4);
    short2 a = pk2(f.x, f.y), b = pk2(f.z, f.w);
    short4 o = {a.x, a.y, b.x, b.y};
    *(short4*)&T[r][cs + j * 4] = o;
  }
  __syncthreads();
  short tmp[16];
#pragma unroll
  for (int i = 0; i < 16; ++i) tmp[i] = T[cs + i][r];
  *(int4*)(D + (size_t)(n0 + r) * DM + k0 + cs) = *(const int4*)&tmp[0];
  *(int4*)(D + (size_t)(n0 + r) * DM + k0 + cs + 8) = *(const int4*)&tmp[8];
}

// ---------- GEMM (r8 512-thr form): Y = A @ Bt^T + bias ----------
// 512 threads (8 waves), 128x128 tile, BK=32, dbuf, 1 barrier/iter.
// Wave w: wa=w&1 m-half (4 tiles), wb=w>>1 n-quarter (2 tiles).
// MODE 0: z<2 headsplit bf16 [b][h][t][dk] scalar coalesced (z==0 folds
//   QSCALE); z==2 V^T [b][h][dk][t] in F16 (short4 over 4 consecutive t).
// MODE 1: flat fp32, scalar coalesced.
template <int MODE>
__global__ __launch_bounds__(512) void gemm_bt(
    const short* __restrict__ A_, const short* __restrict__ Bt_,
    const float* __restrict__ b0, const float* __restrict__ b1,
    const float* __restrict__ b2, short* __restrict__ Y,
    float* __restrict__ Yf) {
  __shared__ short As[2][4096];
  __shared__ short Bs[2][4096];
  const int z = (MODE == 0) ? blockIdx.z : 0;
  const short* A = A_ + (size_t)z * (M_ROWS * DM);
  const short* Bt = Bt_ + (size_t)z * (DM * DM);
  short* Yz = (MODE == 0) ? (Y + (size_t)z * ((size_t)M_ROWS * DM)) : Y;
  const float* bias = (MODE == 0) ? (z == 0 ? b0 : (z == 1 ? b1 : b2)) : b0;
  const int m0 = blockIdx.x * 128, n0 = blockIdx.y * 128;
  const int tid = threadIdx.x, w = tid >> 6, lane = tid & 63;
  const int quad = lane >> 4, lm = lane & 15, wa = w & 1, wb = w >> 1;

  const short* Ag = A + (size_t)(m0 + w * 16 + lm) * DM + quad * 8;
  const short* Bg = Bt + (size_t)(n0 + w * 16 + lm) * DM + quad * 8;

  f32x4 acc[4][2];
#pragma unroll
  for (int i = 0; i < 4; ++i)
#pragma unroll
    for (int j = 0; j < 2; ++j) acc[i][j] = (f32x4){0.f, 0.f, 0.f, 0.f};

  GLD16(Ag, &As[0][w * 512]);
  GLD16(Bg, &Bs[0][w * 512]);

  for (int kt = 0; kt < DM / 32; ++kt) {
    const int cb = kt & 1;
    __syncthreads();
    if (kt + 1 < DM / 32) {
      GLD16(Ag + (kt + 1) * 32, &As[cb ^ 1][w * 512]);
      GLD16(Bg + (kt + 1) * 32, &Bs[cb ^ 1][w * 512]);
    }
    bf16x8 af[4], bfr[2];
#pragma unroll
    for (int i = 0; i < 4; ++i)
      af[i] = *(const bf16x8*)&As[cb][(wa * 4 + i) * 512 + quad * 128 + lm * 8];
#pragma unroll
    for (int j = 0; j < 2; ++j)
      bfr[j] = *(const bf16x8*)&Bs[cb][(wb * 2 + j) * 512 + quad * 128 + lm * 8];
#pragma unroll
    for (int mi = 0; mi < 4; ++mi)
#pragma unroll
      for (int j = 0; j < 2; ++j)
        acc[mi][j] = __builtin_amdgcn_mfma_f32_16x16x32_bf16(
            af[mi], bfr[j], acc[mi][j], 0, 0, 0);
  }

  if (MODE == 0 && z < 2) {  // headsplit bf16, coalesced across lm
#pragma unroll
    for (int j = 0; j < 2; ++j) {
      const int f = n0 + (wb * 2 + j) * 16 + lm;
      const float bv = bias[f];
      const int h = f >> 6, dk = f & 63;
#pragma unroll
      for (int mi = 0; mi < 4; ++mi)
#pragma unroll
        for (int r = 0; r < 4; ++r) {
          const int m = m0 + (wa * 4 + mi) * 16 + quad * 4 + r;
          float val = acc[mi][j][r] + bv;
          if (z == 0) val *= QSCALE;
          const int b = m >> 11, tt = m & (T_SEQ - 1);
          Yz[(((size_t)(b * NH + h) << 11) + tt) * DKH + dk] = f2bf(val);
        }
    }
  } else if (MODE == 0) {  // z==2: V^T [b][h][dk][t] in F16, 4 consecutive t
#pragma unroll
    for (int j = 0; j < 2; ++j) {
      const int f = n0 + (wb * 2 + j) * 16 + lm;
      const float bv = bias[f];
      const int h = f >> 6, dk = f & 63;
#pragma unroll
      for (int mi = 0; mi < 4; ++mi) {
        const int t = m0 + (wa * 4 + mi) * 16 + quad * 4;
        const int b = t >> 11, tt = t & (T_SEQ - 1);
        short2 a = pkh(acc[mi][j][0] + bv, acc[mi][j][1] + bv);
        short2 c = pkh(acc[mi][j][2] + bv, acc[mi][j][3] + bv);
        short4 o = {a.x, a.y, c.x, c.y};
        *(short4*)(Yz + (((size_t)(b * NH + h) * DKH + dk) << 11) + tt) = o;
      }
    }
  } else {  // MODE 1: fp32, coalesced across lm
#pragma unroll
    for (int j = 0; j < 2; ++j) {
      const int n = n0 + (wb * 2 + j) * 16 + lm;
      const float bv = bias[n];
#pragma unroll
      for (int mi = 0; mi < 4; ++mi)
#pragma unroll
        for (int r = 0; r < 4; ++r) {
          const int m = m0 + (wa * 4 + mi) * 16 + quad * 4 + r;
          Yf[(size_t)m * DM + n] = acc[mi][j][r] + bv;
        }
    }
  }
}

// ---------- flash attention: 256 thr, q=64/block, dbuf K/V, register P ----------
// Qh (pre-scaled)/Kh: [bh][t][dk] bf16. Vt: [bh][dk][t] F16. mf additive mask.
// S^T = K.Q^T via 16x16x32 bf16 -> per-lane scores p[key=nt*16+quad*4+r][q=lm].
// PV via 16x16x16 f16: B-operand layout B[n=lm][k=quad*4+i] EQUALS the p
// register layout -> no LDS round-trip. A-operand = V^T 8B frags from LDS.
__global__ __launch_bounds__(256) void attn_kernel(
    const short* __restrict__ Qh, const short* __restrict__ Kh,
    const short* __restrict__ Vt, const float* __restrict__ mf,
    short* __restrict__ Ao) {
  __shared__ short Ks[2][4096];
  __shared__ short Vs[2][4096];
  const int qt = blockIdx.x, bh = blockIdx.y;
  const int b = bh >> 4, h = bh & (NH - 1);
  const int tid = threadIdx.x, w = tid >> 6, lane = tid & 63;
  const int quad = lane >> 4, lm = lane & 15;
  const size_t base = (size_t)bh * T_SEQ * DKH;
  const float* mp = mf + b * T_SEQ;
  const int q0 = qt * 64 + w * 16;

  const short* qp = Qh + base + (size_t)(q0 + lm) * DKH;
  const bf16x8 qb0 = *(const bf16x8*)(qp + quad * 8);
  const bf16x8 qb1 = *(const bf16x8*)(qp + 32 + quad * 8);

  // staging: wave w covers rows w*16+lm of K (dk halves) and of V^T (key halves)
  const short* Kg = Kh + base + (size_t)(w * 16 + lm) * DKH + quad * 8;
  const short* Vg = Vt + base + (size_t)(w * 16 + lm) * T_SEQ + quad * 8;

  f32x4 ot[4];
#pragma unroll
  for (int i = 0; i < 4; ++i) ot[i] = (f32x4){0.f, 0.f, 0.f, 0.f};
  float l_part = 0.f;

  GLD16(Kg, &Ks[0][w * 1024]);
  GLD16(Kg + 32, &Ks[0][w * 1024 + 512]);
  GLD16(Vg, &Vs[0][w * 1024]);
  GLD16(Vg + 32, &Vs[0][w * 1024 + 512]);

  for (int kt = 0; kt < T_SEQ / 64; ++kt) {
    const int cb = kt & 1;
    const int key0 = kt * 64;
    __syncthreads();
    if (kt + 1 < T_SEQ / 64) {
      const int nk = key0 + 64;
      GLD16(Kg + (size_t)nk * DKH, &Ks[cb ^ 1][w * 1024]);
      GLD16(Kg + (size_t)nk * DKH + 32, &Ks[cb ^ 1][w * 1024 + 512]);
      GLD16(Vg + nk, &Vs[cb ^ 1][w * 1024]);
      GLD16(Vg + nk + 32, &Vs[cb ^ 1][w * 1024 + 512]);
    }

    halfx4 pb[4];
#pragma unroll
    for (int nt = 0; nt < 4; ++nt) {
      bf16x8 ka0 = *(const bf16x8*)&Ks[cb][nt * 1024 + quad * 128 + lm * 8];
      bf16x8 ka1 = *(const bf16x8*)&Ks[cb][nt * 1024 + 512 + quad * 128 + lm * 8];
      f32x4 s = (f32x4){0.f, 0.f, 0.f, 0.f};
      s = __builtin_amdgcn_mfma_f32_16x16x32_bf16(ka0, qb0, s, 0, 0, 0);
      s = __builtin_amdgcn_mfma_f32_16x16x32_bf16(ka1, qb1, s, 0, 0, 0);
      const float4 m4 = *(const float4*)(mp + key0 + nt * 16 + quad * 4);
      float p0 = fexp2(s[0] + m4.x);
      float p1 = fexp2(s[1] + m4.y);
      float p2 = fexp2(s[2] + m4.z);
      float p3 = fexp2(s[3] + m4.w);
      l_part += (p0 + p1) + (p2 + p3);
      short2 a = pkh(p0, p1), c = pkh(p2, p3);
      int2 packed = {(int)(unsigned short)a.x | ((int)(unsigned short)a.y << 16),
                     (int)(unsigned short)c.x | ((int)(unsigned short)c.y << 16)};
      pb[nt] = __builtin_bit_cast(halfx4, packed);
    }

    // O^T += V^T . P^T : A = V^T[d=nt2*16+lm][key=nt*16+quad*4+i] (8B frags)
#pragma unroll
    for (int nt2 = 0; nt2 < 4; ++nt2) {
#pragma unroll
      for (int nt = 0; nt < 4; ++nt) {
        const int koff = ((nt & 2) ? 512 : 0) + (2 * (nt & 1) + (quad >> 1)) * 128 +
                         lm * 8 + (quad & 1) * 4;
        halfx4 va = *(const halfx4*)&Vs[cb][nt2 * 1024 + koff];
        ot[nt2] = MFMA16F16(va, pb[nt], ot[nt2], 0, 0, 0);
      }
    }
  }
  l_part += __shfl_xor(l_part, 16, 64);
  l_part += __shfl_xor(l_part, 32, 64);
  const float inv = 1.f / l_part;
  const size_t row = (size_t)(b * T_SEQ + q0 + lm) * DM + h * DKH;
#pragma unroll
  for (int nt = 0; nt < 4; ++nt) {
    short2 a = pk2(ot[nt][0] * inv, ot[nt][1] * inv);
    short2 c = pk2(ot[nt][2] * inv, ot[nt][3] * inv);
    short4 o4 = {a.x, a.y, c.x, c.y};
    *(short4*)(Ao + row + nt * 16 + quad * 4) = o4;
  }
}

extern "C" void kernel_launch(void* const* d_in, const int* in_sizes, int n_in,
                              void* d_out, int out_size, void* d_ws, size_t ws_size,
                              hipStream_t stream) {
  const float* q = (const float*)d_in[0];
  const float* k = (const float*)d_in[1];
  const float* v = (const float*)d_in[2];
  const int* mk = (const int*)d_in[3];
  const float* Wq = (const float*)d_in[4];
  const float* bq = (const float*)d_in[5];
  const float* Wk = (const float*)d_in[6];
  const float* bk = (const float*)d_in[7];
  const float* Wv = (const float*)d_in[8];
  const float* bv = (const float*)d_in[9];
  const float* Wo = (const float*)d_in[10];
  const float* bo = (const float*)d_in[11];

  const size_t XE = (size_t)M_ROWS * DM;  // 4194304
  const size_t WE = (size_t)DM * DM;      // 1048576
  short* xb = (short*)d_ws;               // 3*XE (dead after QKV gemm)
  short* Wt = xb + 3 * XE;                // 4*WE
  short* Qh = Wt + 4 * WE;                // 3*XE: Qh, Kh, Vt(f16)
  float* mf = (float*)(Qh + 3 * XE);      // 4096 floats
  short* Ao = xb;                         // alias

  prep_x<<<dim3(1024, 1, 3), 256, 0, stream>>>(q, k, v, mk, xb, mf);
  prep_w<<<dim3(16, 16, 4), 256, 0, stream>>>(Wq, Wk, Wv, Wo, Wt);
  gemm_bt<0><<<dim3(M_ROWS / 128, DM / 128, 3), 512, 0, stream>>>(
      xb, Wt, bq, bk, bv, Qh, nullptr);
  attn_kernel<<<dim3(T_SEQ / 64, NB * NH), 256, 0, stream>>>(
      Qh, Qh + XE, Qh + 2 * XE, mf, Ao);
  gemm_bt<1><<<dim3(M_ROWS / 128, DM / 128, 1), 512, 0, stream>>>(
      Ao, Wt + 3 * WE, bo, nullptr, nullptr, nullptr, (float*)d_out);
}

// Round 13
// 291.326 us; speedup vs baseline: 1.0476x; 1.0476x over previous
//
#include <hip/hip_runtime.h>

#define T_SEQ 2048
#define DM 1024
#define NH 16
#define DKH 64
#define NB 2
#define M_ROWS (NB * T_SEQ)  // 4096
#define QSCALE 0.18033688011112042f  // 0.125 * log2(e): exp2 domain

using bf16x8 = __attribute__((ext_vector_type(8))) __bf16;
using f32x4  = __attribute__((ext_vector_type(4))) float;
using halfx4 = __attribute__((ext_vector_type(4))) __fp16;
using halfx2 = __attribute__((ext_vector_type(2))) __fp16;

__device__ __forceinline__ short f2bf(float f) {
  unsigned u = __builtin_bit_cast(unsigned, f);
  u += 0x7fffu + ((u >> 16) & 1u);
  return (short)(u >> 16);
}

#if defined(__has_builtin) && __has_builtin(__builtin_amdgcn_cvt_pk_bf16_f32)
using bf16x2 = __attribute__((ext_vector_type(2))) __bf16;
__device__ __forceinline__ short2 pk2(float a, float b) {
  bf16x2 r = __builtin_amdgcn_cvt_pk_bf16_f32(a, b);
  return __builtin_bit_cast(short2, r);
}
#else
__device__ __forceinline__ short2 pk2(float a, float b) {
  short2 r; r.x = f2bf(a); r.y = f2bf(b); return r;
}
#endif

__device__ __forceinline__ short2 pkh(float a, float b) {  // f32x2 -> f16x2 (RTZ)
  halfx2 r = __builtin_amdgcn_cvt_pkrtz(a, b);
  return __builtin_bit_cast(short2, r);
}

#if defined(__has_builtin) && __has_builtin(__builtin_amdgcn_exp2f)
__device__ __forceinline__ float fexp2(float x) { return __builtin_amdgcn_exp2f(x); }
#else
__device__ __forceinline__ float fexp2(float x) { return exp2f(x); }
#endif

#define MFMA16F16 __builtin_amdgcn_mfma_f32_16x16x16f16

#define GLD16(g, l)                                                            \
  __builtin_amdgcn_global_load_lds(                                            \
      (const __attribute__((address_space(1))) void*)(g),                      \
      (__attribute__((address_space(3))) void*)(l), 16, 0, 0)

// ---------- prep: fp32 -> bf16 of q,k,v; mask -> additive float ----------
__global__ __launch_bounds__(256) void prep_x(
    const float* __restrict__ q, const float* __restrict__ k,
    const float* __restrict__ v, const int* __restrict__ mask,
    short* __restrict__ dst, float* __restrict__ mf) {
  const float* s = blockIdx.z == 0 ? q : (blockIdx.z == 1 ? k : v);
  short* d = dst + (size_t)blockIdx.z * (M_ROWS * DM);
  const int n4 = M_ROWS * DM / 4;
  for (int i = blockIdx.x * 256 + threadIdx.x; i < n4; i += gridDim.x * 256) {
    float4 f = *(const float4*)(s + i * 4);
    short2 a = pk2(f.x, f.y), b = pk2(f.z, f.w);
    short4 o = {a.x, a.y, b.x, b.y};
    *(short4*)(d + i * 4) = o;
  }
  if (blockIdx.z == 0 && blockIdx.x < 4) {
    int i = (blockIdx.x * 256 + threadIdx.x) * 4;
    int4 m = *(const int4*)(mask + i);
    float4 o = {m.x ? 0.f : -1e38f, m.y ? 0.f : -1e38f,
                m.z ? 0.f : -1e38f, m.w ? 0.f : -1e38f};
    *(float4*)(mf + i) = o;
  }
}

// ---------- prep: W [k][n] fp32 -> Wt [n][k] bf16 (4 matrices) ----------
__global__ __launch_bounds__(256) void prep_w(
    const float* __restrict__ w0, const float* __restrict__ w1,
    const float* __restrict__ w2, const float* __restrict__ w3,
    short* __restrict__ dst) {
  __shared__ short T[64][72];
  const float* W = blockIdx.z == 0 ? w0 : blockIdx.z == 1 ? w1
                   : blockIdx.z == 2 ? w2 : w3;
  short* D = dst + (size_t)blockIdx.z * (DM * DM);
  const int k0 = blockIdx.x * 64, n0 = blockIdx.y * 64;
  const int r = threadIdx.x >> 2, cs = (threadIdx.x & 3) * 16;
#pragma unroll
  for (int j = 0; j < 4; ++j) {
    float4 f = *(const float4*)(W + (size_t)(k0 + r) * DM + n0 + cs + j * 4);
    short2 a = pk2(f.x, f.y), b = pk2(f.z, f.w);
    short4 o = {a.x, a.y, b.x, b.y};
    *(short4*)&T[r][cs + j * 4] = o;
  }
  __syncthreads();
  short tmp[16];
#pragma unroll
  for (int i = 0; i < 16; ++i) tmp[i] = T[cs + i][r];
  *(int4*)(D + (size_t)(n0 + r) * DM + k0 + cs) = *(const int4*)&tmp[0];
  *(int4*)(D + (size_t)(n0 + r) * DM + k0 + cs + 8) = *(const int4*)&tmp[8];
}

// ---------- GEMM (r8 512-thr form): Y = A @ Bt^T + bias ----------
// 512 threads (8 waves), 128x128 tile, BK=32, dbuf, 1 barrier/iter.
// MODE 0: z<2 headsplit bf16 [b][h][t][dk] scalar coalesced (z==0 folds
//   QSCALE); z==2 V^T [b][h][dk][t] in F16 (short4 over 4 consecutive t).
// MODE 1: flat fp32, scalar coalesced.
template <int MODE>
__global__ __launch_bounds__(512) void gemm_bt(
    const short* __restrict__ A_, const short* __restrict__ Bt_,
    const float* __restrict__ b0, const float* __restrict__ b1,
    const float* __restrict__ b2, short* __restrict__ Y,
    float* __restrict__ Yf) {
  __shared__ short As[2][4096];
  __shared__ short Bs[2][4096];
  const int z = (MODE == 0) ? blockIdx.z : 0;
  const short* A = A_ + (size_t)z * (M_ROWS * DM);
  const short* Bt = Bt_ + (size_t)z * (DM * DM);
  short* Yz = (MODE == 0) ? (Y + (size_t)z * ((size_t)M_ROWS * DM)) : Y;
  const float* bias = (MODE == 0) ? (z == 0 ? b0 : (z == 1 ? b1 : b2)) : b0;
  const int m0 = blockIdx.x * 128, n0 = blockIdx.y * 128;
  const int tid = threadIdx.x, w = tid >> 6, lane = tid & 63;
  const int quad = lane >> 4, lm = lane & 15, wa = w & 1, wb = w >> 1;

  const short* Ag = A + (size_t)(m0 + w * 16 + lm) * DM + quad * 8;
  const short* Bg = Bt + (size_t)(n0 + w * 16 + lm) * DM + quad * 8;

  f32x4 acc[4][2];
#pragma unroll
  for (int i = 0; i < 4; ++i)
#pragma unroll
    for (int j = 0; j < 2; ++j) acc[i][j] = (f32x4){0.f, 0.f, 0.f, 0.f};

  GLD16(Ag, &As[0][w * 512]);
  GLD16(Bg, &Bs[0][w * 512]);

  for (int kt = 0; kt < DM / 32; ++kt) {
    const int cb = kt & 1;
    __syncthreads();
    if (kt + 1 < DM / 32) {
      GLD16(Ag + (kt + 1) * 32, &As[cb ^ 1][w * 512]);
      GLD16(Bg + (kt + 1) * 32, &Bs[cb ^ 1][w * 512]);
    }
    bf16x8 af[4], bfr[2];
#pragma unroll
    for (int i = 0; i < 4; ++i)
      af[i] = *(const bf16x8*)&As[cb][(wa * 4 + i) * 512 + quad * 128 + lm * 8];
#pragma unroll
    for (int j = 0; j < 2; ++j)
      bfr[j] = *(const bf16x8*)&Bs[cb][(wb * 2 + j) * 512 + quad * 128 + lm * 8];
#pragma unroll
    for (int mi = 0; mi < 4; ++mi)
#pragma unroll
      for (int j = 0; j < 2; ++j)
        acc[mi][j] = __builtin_amdgcn_mfma_f32_16x16x32_bf16(
            af[mi], bfr[j], acc[mi][j], 0, 0, 0);
  }

  if (MODE == 0 && z < 2) {  // headsplit bf16, coalesced across lm
#pragma unroll
    for (int j = 0; j < 2; ++j) {
      const int f = n0 + (wb * 2 + j) * 16 + lm;
      const float bv = bias[f];
      const int h = f >> 6, dk = f & 63;
#pragma unroll
      for (int mi = 0; mi < 4; ++mi)
#pragma unroll
        for (int r = 0; r < 4; ++r) {
          const int m = m0 + (wa * 4 + mi) * 16 + quad * 4 + r;
          float val = acc[mi][j][r] + bv;
          if (z == 0) val *= QSCALE;
          const int b = m >> 11, tt = m & (T_SEQ - 1);
          Yz[(((size_t)(b * NH + h) << 11) + tt) * DKH + dk] = f2bf(val);
        }
    }
  } else if (MODE == 0) {  // z==2: V^T [b][h][dk][t] in F16, 4 consecutive t
#pragma unroll
    for (int j = 0; j < 2; ++j) {
      const int f = n0 + (wb * 2 + j) * 16 + lm;
      const float bv = bias[f];
      const int h = f >> 6, dk = f & 63;
#pragma unroll
      for (int mi = 0; mi < 4; ++mi) {
        const int t = m0 + (wa * 4 + mi) * 16 + quad * 4;
        const int b = t >> 11, tt = t & (T_SEQ - 1);
        short2 a = pkh(acc[mi][j][0] + bv, acc[mi][j][1] + bv);
        short2 c = pkh(acc[mi][j][2] + bv, acc[mi][j][3] + bv);
        short4 o = {a.x, a.y, c.x, c.y};
        *(short4*)(Yz + (((size_t)(b * NH + h) * DKH + dk) << 11) + tt) = o;
      }
    }
  } else {  // MODE 1: fp32, coalesced across lm
#pragma unroll
    for (int j = 0; j < 2; ++j) {
      const int n = n0 + (wb * 2 + j) * 16 + lm;
      const float bv = bias[n];
#pragma unroll
      for (int mi = 0; mi < 4; ++mi)
#pragma unroll
        for (int r = 0; r < 4; ++r) {
          const int m = m0 + (wa * 4 + mi) * 16 + quad * 4 + r;
          Yf[(size_t)m * DM + n] = acc[mi][j][r] + bv;
        }
    }
  }
}

// ---------- flash attention: 512 thr, q=128/block, dbuf K/V, register P ----------
// Qh (pre-scaled)/Kh: [bh][t][dk] bf16. Vt: [bh][dk][t] F16. mf additive mask.
// Waves 0-3 stage K tile, waves 4-7 stage V^T tile (2 GLD16/wave/tile).
// S^T = K.Q^T via 16x16x32 bf16 -> per-lane scores p[key=nt*16+quad*4+r][q=lm].
// PV via 16x16x16 f16: B-operand layout == p register layout (no LDS trip).
__global__ __launch_bounds__(512) void attn_kernel(
    const short* __restrict__ Qh, const short* __restrict__ Kh,
    const short* __restrict__ Vt, const float* __restrict__ mf,
    short* __restrict__ Ao) {
  __shared__ short Ks[2][4096];
  __shared__ short Vs[2][4096];
  const int qt = blockIdx.x, bh = blockIdx.y;
  const int b = bh >> 4, h = bh & (NH - 1);
  const int tid = threadIdx.x, w = tid >> 6, lane = tid & 63;
  const int quad = lane >> 4, lm = lane & 15;
  const size_t base = (size_t)bh * T_SEQ * DKH;
  const float* mp = mf + b * T_SEQ;
  const int q0 = qt * 128 + w * 16;

  const short* qp = Qh + base + (size_t)(q0 + lm) * DKH;
  const bf16x8 qb0 = *(const bf16x8*)(qp + quad * 8);
  const bf16x8 qb1 = *(const bf16x8*)(qp + 32 + quad * 8);

  // staging specialization: waves 0-3 -> K rows sw*16+lm (dk halves);
  // waves 4-7 -> V^T rows sw*16+lm (key halves)
  const int sw = w & 3;
  const bool isV = w >= 4;
  const short* Sg = isV ? (Vt + base + (size_t)(sw * 16 + lm) * T_SEQ + quad * 8)
                        : (Kh + base + (size_t)(sw * 16 + lm) * DKH + quad * 8);

  f32x4 ot[4];
#pragma unroll
  for (int i = 0; i < 4; ++i) ot[i] = (f32x4){0.f, 0.f, 0.f, 0.f};
  float l_part = 0.f;

  {
    short* d0 = isV ? &Vs[0][sw * 1024] : &Ks[0][sw * 1024];
    GLD16(Sg, d0);
    GLD16(Sg + 32, d0 + 512);
  }

  for (int kt = 0; kt < T_SEQ / 64; ++kt) {
    const int cb = kt & 1;
    const int key0 = kt * 64;
    __syncthreads();
    if (kt + 1 < T_SEQ / 64) {
      const int nk = key0 + 64;
      short* d0 = isV ? &Vs[cb ^ 1][sw * 1024] : &Ks[cb ^ 1][sw * 1024];
      const short* s0 = isV ? (Sg + nk) : (Sg + (size_t)nk * DKH);
      GLD16(s0, d0);
      GLD16(s0 + 32, d0 + 512);
    }

    halfx4 pb[4];
#pragma unroll
    for (int nt = 0; nt < 4; ++nt) {
      bf16x8 ka0 = *(const bf16x8*)&Ks[cb][nt * 1024 + quad * 128 + lm * 8];
      bf16x8 ka1 = *(const bf16x8*)&Ks[cb][nt * 1024 + 512 + quad * 128 + lm * 8];
      f32x4 s = (f32x4){0.f, 0.f, 0.f, 0.f};
      s = __builtin_amdgcn_mfma_f32_16x16x32_bf16(ka0, qb0, s, 0, 0, 0);
      s = __builtin_amdgcn_mfma_f32_16x16x32_bf16(ka1, qb1, s, 0, 0, 0);
      const float4 m4 = *(const float4*)(mp + key0 + nt * 16 + quad * 4);
      float p0 = fexp2(s[0] + m4.x);
      float p1 = fexp2(s[1] + m4.y);
      float p2 = fexp2(s[2] + m4.z);
      float p3 = fexp2(s[3] + m4.w);
      l_part += (p0 + p1) + (p2 + p3);
      short2 a = pkh(p0, p1), c = pkh(p2, p3);
      int2 packed = {(int)(unsigned short)a.x | ((int)(unsigned short)a.y << 16),
                     (int)(unsigned short)c.x | ((int)(unsigned short)c.y << 16)};
      pb[nt] = __builtin_bit_cast(halfx4, packed);
    }

    // O^T += V^T . P^T : A = V^T[d=nt2*16+lm][key=nt*16+quad*4+i] (8B frags)
#pragma unroll
    for (int nt2 = 0; nt2 < 4; ++nt2) {
#pragma unroll
      for (int nt = 0; nt < 4; ++nt) {
        const int koff = ((nt & 2) ? 512 : 0) + (2 * (nt & 1) + (quad >> 1)) * 128 +
                         lm * 8 + (quad & 1) * 4;
        halfx4 va = *(const halfx4*)&Vs[cb][nt2 * 1024 + koff];
        ot[nt2] = MFMA16F16(va, pb[nt], ot[nt2], 0, 0, 0);
      }
    }
  }
  l_part += __shfl_xor(l_part, 16, 64);
  l_part += __shfl_xor(l_part, 32, 64);
  const float inv = 1.f / l_part;
  const size_t row = (size_t)(b * T_SEQ + q0 + lm) * DM + h * DKH;
#pragma unroll
  for (int nt = 0; nt < 4; ++nt) {
    short2 a = pk2(ot[nt][0] * inv, ot[nt][1] * inv);
    short2 c = pk2(ot[nt][2] * inv, ot[nt][3] * inv);
    short4 o4 = {a.x, a.y, c.x, c.y};
    *(short4*)(Ao + row + nt * 16 + quad * 4) = o4;
  }
}

extern "C" void kernel_launch(void* const* d_in, const int* in_sizes, int n_in,
                              void* d_out, int out_size, void* d_ws, size_t ws_size,
                              hipStream_t stream) {
  const float* q = (const float*)d_in[0];
  const float* k = (const float*)d_in[1];
  const float* v = (const float*)d_in[2];
  const int* mk = (const int*)d_in[3];
  const float* Wq = (const float*)d_in[4];
  const float* bq = (const float*)d_in[5];
  const float* Wk = (const float*)d_in[6];
  const float* bk = (const float*)d_in[7];
  const float* Wv = (const float*)d_in[8];
  const float* bv = (const float*)d_in[9];
  const float* Wo = (const float*)d_in[10];
  const float* bo = (const float*)d_in[11];

  const size_t XE = (size_t)M_ROWS * DM;  // 4194304
  const size_t WE = (size_t)DM * DM;      // 1048576
  short* xb = (short*)d_ws;               // 3*XE (dead after QKV gemm)
  short* Wt = xb + 3 * XE;                // 4*WE
  short* Qh = Wt + 4 * WE;                // 3*XE: Qh, Kh, Vt(f16)
  float* mf = (float*)(Qh + 3 * XE);      // 4096 floats
  short* Ao = xb;                         // alias

  prep_x<<<dim3(1024, 1, 3), 256, 0, stream>>>(q, k, v, mk, xb, mf);
  prep_w<<<dim3(16, 16, 4), 256, 0, stream>>>(Wq, Wk, Wv, Wo, Wt);
  gemm_bt<0><<<dim3(M_ROWS / 128, DM / 128, 3), 512, 0, stream>>>(
      xb, Wt, bq, bk, bv, Qh, nullptr);
  attn_kernel<<<dim3(T_SEQ / 128, NB * NH), 512, 0, stream>>>(
      Qh, Qh + XE, Qh + 2 * XE, mf, Ao);
  gemm_bt<1><<<dim3(M_ROWS / 128, DM / 128, 1), 512, 0, stream>>>(
      Ao, Wt + 3 * WE, bo, nullptr, nullptr, nullptr, (float*)d_out);
}

// Round 14
// 264.294 us; speedup vs baseline: 1.1547x; 1.1023x over previous
//
#include <hip/hip_runtime.h>

#define T_SEQ 2048
#define DM 1024
#define NH 16
#define DKH 64
#define NB 2
#define M_ROWS (NB * T_SEQ)  // 4096
#define QSCALE 0.18033688011112042f  // 0.125 * log2(e): exp2 domain

using bf16x8 = __attribute__((ext_vector_type(8))) __bf16;
using f32x4  = __attribute__((ext_vector_type(4))) float;
using halfx4 = __attribute__((ext_vector_type(4))) __fp16;
using halfx2 = __attribute__((ext_vector_type(2))) __fp16;

__device__ __forceinline__ short f2bf(float f) {
  unsigned u = __builtin_bit_cast(unsigned, f);
  u += 0x7fffu + ((u >> 16) & 1u);
  return (short)(u >> 16);
}

#if defined(__has_builtin) && __has_builtin(__builtin_amdgcn_cvt_pk_bf16_f32)
using bf16x2 = __attribute__((ext_vector_type(2))) __bf16;
__device__ __forceinline__ short2 pk2(float a, float b) {
  bf16x2 r = __builtin_amdgcn_cvt_pk_bf16_f32(a, b);
  return __builtin_bit_cast(short2, r);
}
#else
__device__ __forceinline__ short2 pk2(float a, float b) {
  short2 r; r.x = f2bf(a); r.y = f2bf(b); return r;
}
#endif

__device__ __forceinline__ short2 pkh(float a, float b) {  // f32x2 -> f16x2 (RTZ)
  halfx2 r = __builtin_amdgcn_cvt_pkrtz(a, b);
  return __builtin_bit_cast(short2, r);
}

#if defined(__has_builtin) && __has_builtin(__builtin_amdgcn_exp2f)
__device__ __forceinline__ float fexp2(float x) { return __builtin_amdgcn_exp2f(x); }
#else
__device__ __forceinline__ float fexp2(float x) { return exp2f(x); }
#endif

#define MFMA16F16 __builtin_amdgcn_mfma_f32_16x16x16f16

#define GLD16(g, l)                                                            \
  __builtin_amdgcn_global_load_lds(                                            \
      (const __attribute__((address_space(1))) void*)(g),                      \
      (__attribute__((address_space(3))) void*)(l), 16, 0, 0)

// ---------- prep: fp32 -> bf16 of q,k,v; mask -> additive float ----------
__global__ __launch_bounds__(256) void prep_x(
    const float* __restrict__ q, const float* __restrict__ k,
    const float* __restrict__ v, const int* __restrict__ mask,
    short* __restrict__ dst, float* __restrict__ mf) {
  const float* s = blockIdx.z == 0 ? q : (blockIdx.z == 1 ? k : v);
  short* d = dst + (size_t)blockIdx.z * (M_ROWS * DM);
  const int n4 = M_ROWS * DM / 4;
  for (int i = blockIdx.x * 256 + threadIdx.x; i < n4; i += gridDim.x * 256) {
    float4 f = *(const float4*)(s + i * 4);
    short2 a = pk2(f.x, f.y), b = pk2(f.z, f.w);
    short4 o = {a.x, a.y, b.x, b.y};
    *(short4*)(d + i * 4) = o;
  }
  if (blockIdx.z == 0 && blockIdx.x < 4) {
    int i = (blockIdx.x * 256 + threadIdx.x) * 4;
    int4 m = *(const int4*)(mask + i);
    float4 o = {m.x ? 0.f : -1e38f, m.y ? 0.f : -1e38f,
                m.z ? 0.f : -1e38f, m.w ? 0.f : -1e38f};
    *(float4*)(mf + i) = o;
  }
}

// ---------- prep: W [k][n] fp32 -> Wt [n][k] bf16 (4 matrices) ----------
__global__ __launch_bounds__(256) void prep_w(
    const float* __restrict__ w0, const float* __restrict__ w1,
    const float* __restrict__ w2, const float* __restrict__ w3,
    short* __restrict__ dst) {
  __shared__ short T[64][72];
  const float* W = blockIdx.z == 0 ? w0 : blockIdx.z == 1 ? w1
                   : blockIdx.z == 2 ? w2 : w3;
  short* D = dst + (size_t)blockIdx.z * (DM * DM);
  const int k0 = blockIdx.x * 64, n0 = blockIdx.y * 64;
  const int r = threadIdx.x >> 2, cs = (threadIdx.x & 3) * 16;
#pragma unroll
  for (int j = 0; j < 4; ++j) {
    float4 f = *(const float4*)(W + (size_t)(k0 + r) * DM + n0 + cs + j * 4);
    short2 a = pk2(f.x, f.y), b = pk2(f.z, f.w);
    short4 o = {a.x, a.y, b.x, b.y};
    *(short4*)&T[r][cs + j * 4] = o;
  }
  __syncthreads();
  short tmp[16];
#pragma unroll
  for (int i = 0; i < 16; ++i) tmp[i] = T[cs + i][r];
  *(int4*)(D + (size_t)(n0 + r) * DM + k0 + cs) = *(const int4*)&tmp[0];
  *(int4*)(D + (size_t)(n0 + r) * DM + k0 + cs + 8) = *(const int4*)&tmp[8];
}

// ---------- QKV GEMM (r8 512-thr form, proven): Y = A @ Bt^T + bias ----------
// z<2: headsplit bf16 [b][h][t][dk] scalar coalesced (z==0 folds QSCALE);
// z==2: V^T [b][h][dk][t] in F16 (short4 over 4 consecutive t).
__global__ __launch_bounds__(512) void gemm_qkv(
    const short* __restrict__ A_, const short* __restrict__ Bt_,
    const float* __restrict__ b0, const float* __restrict__ b1,
    const float* __restrict__ b2, short* __restrict__ Y) {
  __shared__ short As[2][4096];
  __shared__ short Bs[2][4096];
  const int z = blockIdx.z;
  const short* A = A_ + (size_t)z * (M_ROWS * DM);
  const short* Bt = Bt_ + (size_t)z * (DM * DM);
  short* Yz = Y + (size_t)z * ((size_t)M_ROWS * DM);
  const float* bias = z == 0 ? b0 : (z == 1 ? b1 : b2);
  const int m0 = blockIdx.x * 128, n0 = blockIdx.y * 128;
  const int tid = threadIdx.x, w = tid >> 6, lane = tid & 63;
  const int quad = lane >> 4, lm = lane & 15, wa = w & 1, wb = w >> 1;

  const short* Ag = A + (size_t)(m0 + w * 16 + lm) * DM + quad * 8;
  const short* Bg = Bt + (size_t)(n0 + w * 16 + lm) * DM + quad * 8;

  f32x4 acc[4][2];
#pragma unroll
  for (int i = 0; i < 4; ++i)
#pragma unroll
    for (int j = 0; j < 2; ++j) acc[i][j] = (f32x4){0.f, 0.f, 0.f, 0.f};

  GLD16(Ag, &As[0][w * 512]);
  GLD16(Bg, &Bs[0][w * 512]);

  for (int kt = 0; kt < DM / 32; ++kt) {
    const int cb = kt & 1;
    __syncthreads();
    if (kt + 1 < DM / 32) {
      GLD16(Ag + (kt + 1) * 32, &As[cb ^ 1][w * 512]);
      GLD16(Bg + (kt + 1) * 32, &Bs[cb ^ 1][w * 512]);
    }
    bf16x8 af[4], bfr[2];
#pragma unroll
    for (int i = 0; i < 4; ++i)
      af[i] = *(const bf16x8*)&As[cb][(wa * 4 + i) * 512 + quad * 128 + lm * 8];
#pragma unroll
    for (int j = 0; j < 2; ++j)
      bfr[j] = *(const bf16x8*)&Bs[cb][(wb * 2 + j) * 512 + quad * 128 + lm * 8];
#pragma unroll
    for (int mi = 0; mi < 4; ++mi)
#pragma unroll
      for (int j = 0; j < 2; ++j)
        acc[mi][j] = __builtin_amdgcn_mfma_f32_16x16x32_bf16(
            af[mi], bfr[j], acc[mi][j], 0, 0, 0);
  }

  if (z < 2) {
#pragma unroll
    for (int j = 0; j < 2; ++j) {
      const int f = n0 + (wb * 2 + j) * 16 + lm;
      const float bv = bias[f];
      const int h = f >> 6, dk = f & 63;
#pragma unroll
      for (int mi = 0; mi < 4; ++mi)
#pragma unroll
        for (int r = 0; r < 4; ++r) {
          const int m = m0 + (wa * 4 + mi) * 16 + quad * 4 + r;
          float val = acc[mi][j][r] + bv;
          if (z == 0) val *= QSCALE;
          const int b = m >> 11, tt = m & (T_SEQ - 1);
          Yz[(((size_t)(b * NH + h) << 11) + tt) * DKH + dk] = f2bf(val);
        }
    }
  } else {  // V^T [b][h][dk][t] F16
#pragma unroll
    for (int j = 0; j < 2; ++j) {
      const int f = n0 + (wb * 2 + j) * 16 + lm;
      const float bv = bias[f];
      const int h = f >> 6, dk = f & 63;
#pragma unroll
      for (int mi = 0; mi < 4; ++mi) {
        const int t = m0 + (wa * 4 + mi) * 16 + quad * 4;
        const int b = t >> 11, tt = t & (T_SEQ - 1);
        short2 a = pkh(acc[mi][j][0] + bv, acc[mi][j][1] + bv);
        short2 c = pkh(acc[mi][j][2] + bv, acc[mi][j][3] + bv);
        short4 o = {a.x, a.y, c.x, c.y};
        *(short4*)(Yz + (((size_t)(b * NH + h) * DKH + dk) << 11) + tt) = o;
      }
    }
  }
}

// ---------- out-proj GEMM: 128x64 tile, 512 thr, 512 blocks (2/CU) ----------
__global__ __launch_bounds__(512) void gemm_out(
    const short* __restrict__ A, const short* __restrict__ Bt,
    const float* __restrict__ bias, float* __restrict__ Yf) {
  __shared__ short As[2][4096];
  __shared__ short Bs[2][2048];
  const int m0 = blockIdx.x * 128, n0 = blockIdx.y * 64;
  const int tid = threadIdx.x, w = tid >> 6, lane = tid & 63;
  const int quad = lane >> 4, lm = lane & 15, wa = w & 3, wb = w >> 2;

  const short* Ag = A + (size_t)(m0 + w * 16 + lm) * DM + quad * 8;
  const short* Bg = Bt + (size_t)(n0 + (w & 3) * 16 + lm) * DM + quad * 8;

  f32x4 acc[2][2];
#pragma unroll
  for (int i = 0; i < 2; ++i)
#pragma unroll
    for (int j = 0; j < 2; ++j) acc[i][j] = (f32x4){0.f, 0.f, 0.f, 0.f};

  GLD16(Ag, &As[0][w * 512]);
  if (w < 4) GLD16(Bg, &Bs[0][w * 512]);

  for (int kt = 0; kt < DM / 32; ++kt) {
    const int cb = kt & 1;
    __syncthreads();
    if (kt + 1 < DM / 32) {
      GLD16(Ag + (kt + 1) * 32, &As[cb ^ 1][w * 512]);
      if (w < 4) GLD16(Bg + (kt + 1) * 32, &Bs[cb ^ 1][w * 512]);
    }
    bf16x8 af[2], bfr[2];
#pragma unroll
    for (int i = 0; i < 2; ++i)
      af[i] = *(const bf16x8*)&As[cb][(wa * 2 + i) * 512 + quad * 128 + lm * 8];
#pragma unroll
    for (int j = 0; j < 2; ++j)
      bfr[j] = *(const bf16x8*)&Bs[cb][(wb * 2 + j) * 512 + quad * 128 + lm * 8];
#pragma unroll
    for (int mi = 0; mi < 2; ++mi)
#pragma unroll
      for (int j = 0; j < 2; ++j)
        acc[mi][j] = __builtin_amdgcn_mfma_f32_16x16x32_bf16(
            af[mi], bfr[j], acc[mi][j], 0, 0, 0);
  }

#pragma unroll
  for (int j = 0; j < 2; ++j) {
    const int n = n0 + (wb * 2 + j) * 16 + lm;
    const float bv = bias[n];
#pragma unroll
    for (int mi = 0; mi < 2; ++mi)
#pragma unroll
      for (int r = 0; r < 4; ++r) {
        const int m = m0 + (wa * 2 + mi) * 16 + quad * 4 + r;
        Yf[(size_t)m * DM + n] = acc[mi][j][r] + bv;
      }
  }
}

// ---------- flash attention: 512 thr, q=128, 128-key tiles, XCD swizzle ----------
// Qh (pre-scaled)/Kh: [bh][t][dk] bf16. Vt: [bh][dk][t] F16. mf additive mask.
// Swizzle: id = bx + gx*by; bh = id&31, qt = id>>5 -> all 16 q-tiles of a head
// on one XCD (K/V L2-resident, ~2 MB/XCD). Waves 0-3 stage K, 4-7 stage V^T
// (4 GLD16/wave/tile). 16 barriers total. S^T = K.Q^T; p = exp2(s+mask);
// PV via mfma_f32_16x16x16f16 with P in registers (B-layout match).
__global__ __launch_bounds__(512) void attn_kernel(
    const short* __restrict__ Qh, const short* __restrict__ Kh,
    const short* __restrict__ Vt, const float* __restrict__ mf,
    short* __restrict__ Ao) {
  __shared__ short Ks[2][8192];
  __shared__ short Vs[2][8192];
  const int id = blockIdx.x + gridDim.x * blockIdx.y;
  const int bh = id & 31, qt = id >> 5;
  const int b = bh >> 4, h = bh & (NH - 1);
  const int tid = threadIdx.x, w = tid >> 6, lane = tid & 63;
  const int quad = lane >> 4, lm = lane & 15;
  const size_t base = (size_t)bh * T_SEQ * DKH;
  const float* mp = mf + b * T_SEQ;
  const int q0 = qt * 128 + w * 16;

  const short* qp = Qh + base + (size_t)(q0 + lm) * DKH;
  const bf16x8 qb0 = *(const bf16x8*)(qp + quad * 8);
  const bf16x8 qb1 = *(const bf16x8*)(qp + 32 + quad * 8);

  const int sw = w & 3;
  const bool isV = w >= 4;
  const short* Kg = Kh + base + (size_t)(sw * 16 + lm) * DKH + quad * 8;
  const short* Vg = Vt + base + (size_t)(sw * 16 + lm) * T_SEQ + quad * 8;

  f32x4 ot[4];
#pragma unroll
  for (int i = 0; i < 4; ++i) ot[i] = (f32x4){0.f, 0.f, 0.f, 0.f};
  float l_part = 0.f;

  // stage tile 0 into buffer 0
  if (!isV) {
    GLD16(Kg, &Ks[0][sw * 1024]);
    GLD16(Kg + 32, &Ks[0][sw * 1024 + 512]);
    GLD16(Kg + (size_t)64 * DKH, &Ks[0][(sw + 4) * 1024]);
    GLD16(Kg + (size_t)64 * DKH + 32, &Ks[0][(sw + 4) * 1024 + 512]);
  } else {
    GLD16(Vg, &Vs[0][sw * 2048]);
    GLD16(Vg + 32, &Vs[0][sw * 2048 + 512]);
    GLD16(Vg + 64, &Vs[0][sw * 2048 + 1024]);
    GLD16(Vg + 96, &Vs[0][sw * 2048 + 1536]);
  }

  for (int kt = 0; kt < T_SEQ / 128; ++kt) {
    const int cb = kt & 1;
    const int key0 = kt * 128;
    __syncthreads();
    if (kt + 1 < T_SEQ / 128) {
      const int nk = key0 + 128;
      if (!isV) {
        GLD16(Kg + (size_t)nk * DKH, &Ks[cb ^ 1][sw * 1024]);
        GLD16(Kg + (size_t)nk * DKH + 32, &Ks[cb ^ 1][sw * 1024 + 512]);
        GLD16(Kg + (size_t)(nk + 64) * DKH, &Ks[cb ^ 1][(sw + 4) * 1024]);
        GLD16(Kg + (size_t)(nk + 64) * DKH + 32, &Ks[cb ^ 1][(sw + 4) * 1024 + 512]);
      } else {
        GLD16(Vg + nk, &Vs[cb ^ 1][sw * 2048]);
        GLD16(Vg + nk + 32, &Vs[cb ^ 1][sw * 2048 + 512]);
        GLD16(Vg + nk + 64, &Vs[cb ^ 1][sw * 2048 + 1024]);
        GLD16(Vg + nk + 96, &Vs[cb ^ 1][sw * 2048 + 1536]);
      }
    }

    halfx4 pb[8];
#pragma unroll
    for (int nt = 0; nt < 8; ++nt) {
      bf16x8 ka0 = *(const bf16x8*)&Ks[cb][nt * 1024 + quad * 128 + lm * 8];
      bf16x8 ka1 = *(const bf16x8*)&Ks[cb][nt * 1024 + 512 + quad * 128 + lm * 8];
      f32x4 s = (f32x4){0.f, 0.f, 0.f, 0.f};
      s = __builtin_amdgcn_mfma_f32_16x16x32_bf16(ka0, qb0, s, 0, 0, 0);
      s = __builtin_amdgcn_mfma_f32_16x16x32_bf16(ka1, qb1, s, 0, 0, 0);
      const float4 m4 = *(const float4*)(mp + key0 + nt * 16 + quad * 4);
      float p0 = fexp2(s[0] + m4.x);
      float p1 = fexp2(s[1] + m4.y);
      float p2 = fexp2(s[2] + m4.z);
      float p3 = fexp2(s[3] + m4.w);
      l_part += (p0 + p1) + (p2 + p3);
      short2 a = pkh(p0, p1), c = pkh(p2, p3);
      int2 packed = {(int)(unsigned short)a.x | ((int)(unsigned short)a.y << 16),
                     (int)(unsigned short)c.x | ((int)(unsigned short)c.y << 16)};
      pb[nt] = __builtin_bit_cast(halfx4, packed);
    }

    // O^T += V^T.P^T : va = V^T[d=nt2*16+lm][key=nt*16+quad*4 .. +3]
#pragma unroll
    for (int nt2 = 0; nt2 < 4; ++nt2) {
#pragma unroll
      for (int nt = 0; nt < 8; ++nt) {
        const int key = nt * 16 + quad * 4;
        const int seg = key >> 5, kis = key & 31;
        halfx4 va = *(const halfx4*)&Vs[cb][nt2 * 2048 + seg * 512 +
                                            (kis >> 3) * 128 + lm * 8 + (kis & 7)];
        ot[nt2] = MFMA16F16(va, pb[nt], ot[nt2], 0, 0, 0);
      }
    }
  }
  l_part += __shfl_xor(l_part, 16, 64);
  l_part += __shfl_xor(l_part, 32, 64);
  const float inv = 1.f / l_part;
  const size_t row = (size_t)(b * T_SEQ + q0 + lm) * DM + h * DKH;
#pragma unroll
  for (int nt = 0; nt < 4; ++nt) {
    short2 a = pk2(ot[nt][0] * inv, ot[nt][1] * inv);
    short2 c = pk2(ot[nt][2] * inv, ot[nt][3] * inv);
    short4 o4 = {a.x, a.y, c.x, c.y};
    *(short4*)(Ao + row + nt * 16 + quad * 4) = o4;
  }
}

extern "C" void kernel_launch(void* const* d_in, const int* in_sizes, int n_in,
                              void* d_out, int out_size, void* d_ws, size_t ws_size,
                              hipStream_t stream) {
  const float* q = (const float*)d_in[0];
  const float* k = (const float*)d_in[1];
  const float* v = (const float*)d_in[2];
  const int* mk = (const int*)d_in[3];
  const float* Wq = (const float*)d_in[4];
  const float* bq = (const float*)d_in[5];
  const float* Wk = (const float*)d_in[6];
  const float* bk = (const float*)d_in[7];
  const float* Wv = (const float*)d_in[8];
  const float* bv = (const float*)d_in[9];
  const float* Wo = (const float*)d_in[10];
  const float* bo = (const float*)d_in[11];

  const size_t XE = (size_t)M_ROWS * DM;  // 4194304
  const size_t WE = (size_t)DM * DM;      // 1048576
  short* xb = (short*)d_ws;               // 3*XE (dead after QKV gemm)
  short* Wt = xb + 3 * XE;                // 4*WE
  short* Qh = Wt + 4 * WE;                // 3*XE: Qh, Kh, Vt(f16)
  float* mf = (float*)(Qh + 3 * XE);      // 4096 floats
  short* Ao = xb;                         // alias

  prep_x<<<dim3(1024, 1, 3), 256, 0, stream>>>(q, k, v, mk, xb, mf);
  prep_w<<<dim3(16, 16, 4), 256, 0, stream>>>(Wq, Wk, Wv, Wo, Wt);
  gemm_qkv<<<dim3(M_ROWS / 128, DM / 128, 3), 512, 0, stream>>>(
      xb, Wt, bq, bk, bv, Qh);
  attn_kernel<<<dim3(T_SEQ / 128, NB * NH), 512, 0, stream>>>(
      Qh, Qh + XE, Qh + 2 * XE, mf, Ao);
  gemm_out<<<dim3(M_ROWS / 128, DM / 64), 512, 0, stream>>>(
      Ao, Wt + 3 * WE, bo, (float*)d_out);
}